// Round 19
// baseline (406.970 us; speedup 1.0000x reference)
//
#include <hip/hip_runtime.h>
#include <math.h>

#define Nn 50000
#define Ee 800000
#define ETe 850000   // E + N self loops
#define Dd 64
#define FIN 128
#define LL 8
#define NB 49        // ceil(Nn/1024)
#define DEGB 3321    // ceil(ETe/256)
#define GEMB 782     // ceil(Nn/64)
#define AGGB 1563    // ceil(Nn/32)

typedef _Float16 f16;
typedef f16 f16x8 __attribute__((ext_vector_type(8)));
typedef float f32x4 __attribute__((ext_vector_type(4)));

__device__ __forceinline__ float hw_to_f(unsigned h) {
  unsigned short b = (unsigned short)(h >> 16);
  f16 w;
  __builtin_memcpy(&w, &b, 2);
  return (float)w;
}

// stats layout: statS/statQ = [8][128] for input map, then per layer L: [8][64]
#define IMSTAT 1024            // 8*128
#define LSTAT(L) (IMSTAT + (L) * 512)   // 8*64 per layer

// ---------------- one-time weight prepack (f16, transposed, padded) ----------------

__global__ __launch_bounds__(256) void k_prep(const float* __restrict__ W1,
    const float* __restrict__ W2, const float* __restrict__ ow1, const float* __restrict__ ow2,
    const float* __restrict__ bwA,
    f16* __restrict__ w1p, f16* __restrict__ w2p, f16* __restrict__ ow1p,
    f16* __restrict__ ow2p, f16* __restrict__ bwp) {
  int id = blockIdx.x * 256 + threadIdx.x;
  f16x8 v;
  if (id < 2176) {
    int n = id / 17, c = id % 17;
    #pragma unroll
    for (int j = 0; j < 8; ++j) v[j] = (c == 16) ? (f16)0.f : (f16)W1[(c * 8 + j) * FIN + n];
    *(f16x8*)&w1p[n * 136 + c * 8] = v;
  } else if (id < 3264) {
    int t2 = id - 2176; int n = t2 / 17, c = t2 % 17;
    #pragma unroll
    for (int j = 0; j < 8; ++j) v[j] = (c == 16) ? (f16)0.f : (f16)W2[(c * 8 + j) * Dd + n];
    *(f16x8*)&w2p[n * 136 + c * 8] = v;
  } else if (id < 4416) {
    int t2 = id - 3264; int n = t2 / 9, c = t2 % 9;
    #pragma unroll
    for (int j = 0; j < 8; ++j) v[j] = (c == 8) ? (f16)0.f : (f16)ow1[(c * 8 + j) * FIN + n];
    *(f16x8*)&ow1p[n * 72 + c * 8] = v;
  } else if (id < 5504) {
    int t2 = id - 4416; int n = t2 / 17, c = t2 % 17;
    #pragma unroll
    for (int j = 0; j < 8; ++j) v[j] = (c == 16) ? (f16)0.f : (f16)ow2[(c * 8 + j) * Dd + n];
    *(f16x8*)&ow2p[n * 136 + c * 8] = v;
  } else if (id < 10112) {
    int t2 = id - 5504; int L = t2 / 576, r = t2 % 576, n = r / 9, c = r % 9;
    #pragma unroll
    for (int j = 0; j < 8; ++j)
      v[j] = (c == 8) ? (f16)0.f : (f16)bwA[L * 4096 + (c * 8 + j) * Dd + n];
    *(f16x8*)&bwp[(size_t)L * 4608 + n * 72 + c * 8] = v;
  }
}

// ---------------- K1: deg (8-way replicated) + ingemm ----------------

__global__ __launch_bounds__(256) void k_build1(const int* __restrict__ ei, int* __restrict__ deg,
    const float* __restrict__ x, const f16* __restrict__ w1p, const float* __restrict__ b1,
    f16* __restrict__ t, float* __restrict__ statS, float* __restrict__ statQ) {
  __shared__ __attribute__((aligned(16))) f16 wt[128 * 136];
  __shared__ float red[256];
  int tid = threadIdx.x;
  if (blockIdx.x < DEGB) {
    int e = blockIdx.x * 256 + tid;
    if (e < ETe) {
      int dst = (e < Ee) ? ei[Ee + e] : (e - Ee);
      atomicAdd(&deg[(blockIdx.x & 7) * Nn + dst], 1);
    }
    return;
  }
  int lane = tid & 63, wid = tid >> 6;
  int row0 = (blockIdx.x - DEGB) * 64;
  red[tid] = 0.f;
  for (int i = tid; i < 2176; i += 256)
    *(f16x8*)&wt[(size_t)i * 8] = *(const f16x8*)&w1p[(size_t)i * 8];
  __syncthreads();
  int rl = lane & 15, kb = lane >> 4;
  int arow = row0 + wid * 16 + rl;
  bool rv = arow < Nn;
  f16x8 afr[4];
  #pragma unroll
  for (int ks = 0; ks < 4; ++ks) {
    float4 p0 = make_float4(0.f, 0.f, 0.f, 0.f), p1 = p0;
    if (rv) {
      p0 = *(const float4*)&x[(size_t)arow * FIN + ks * 32 + kb * 8];
      p1 = *(const float4*)&x[(size_t)arow * FIN + ks * 32 + kb * 8 + 4];
    }
    f16x8 a;
    a[0] = (f16)p0.x; a[1] = (f16)p0.y; a[2] = (f16)p0.z; a[3] = (f16)p0.w;
    a[4] = (f16)p1.x; a[5] = (f16)p1.y; a[6] = (f16)p1.z; a[7] = (f16)p1.w;
    afr[ks] = a;
  }
  f32x4 acc[8];
  #pragma unroll
  for (int i = 0; i < 8; ++i) acc[i] = (f32x4)0.f;
  #pragma unroll
  for (int ks = 0; ks < 4; ++ks) {
    #pragma unroll
    for (int ct = 0; ct < 8; ++ct) {
      f16x8 b = *(const f16x8*)&wt[(ct * 16 + rl) * 136 + ks * 32 + kb * 8];
      acc[ct] = __builtin_amdgcn_mfma_f32_16x16x32_f16(afr[ks], b, acc[ct], 0, 0, 0);
    }
  }
  __syncthreads();   // reuse wt as staging tile ts[64][136]
  f16* ts = wt;
  #pragma unroll
  for (int ct = 0; ct < 8; ++ct) {
    int col = ct * 16 + rl;
    float bv = b1[col];
    float ps = 0.f, pq = 0.f;
    #pragma unroll
    for (int r = 0; r < 4; ++r) {
      int lrow = wid * 16 + kb * 4 + r;
      float v = acc[ct][r] + bv;
      ts[lrow * 136 + col] = (f16)v;
      if (row0 + lrow < Nn) { ps += v; pq += v * v; }
    }
    ps += __shfl_xor(ps, 16, 64); ps += __shfl_xor(ps, 32, 64);
    pq += __shfl_xor(pq, 16, 64); pq += __shfl_xor(pq, 32, 64);
    if (kb == 0) { atomicAdd(&red[col], ps); atomicAdd(&red[128 + col], pq); }
  }
  __syncthreads();
  for (int i = tid; i < 1024; i += 256) {
    int r = i >> 4, c8 = (i & 15) * 8;
    int row = row0 + r;
    if (row < Nn)
      *(f16x8*)(t + (size_t)row * FIN + c8) = *(const f16x8*)&ts[r * 136 + c8];
  }
  if (tid < 128) {
    int slot = (blockIdx.x & 7) * 128 + tid;
    atomicAdd(&statS[slot], red[tid]);
    atomicAdd(&statQ[slot], red[128 + tid]);
  }
}

// ---------------- scan phases ----------------

__global__ __launch_bounds__(1024) void k_scana(const int* __restrict__ deg,
    int* __restrict__ rowptr, int* __restrict__ bsum, float* __restrict__ dinv) {
  __shared__ int wsum[16];
  int tid = threadIdx.x, lane = tid & 63, wid = tid >> 6;
  int i = blockIdx.x * 1024 + tid;
  int v = 0;
  if (i < Nn) {
    #pragma unroll
    for (int sl = 0; sl < 8; ++sl) v += deg[sl * Nn + i];
  }
  int s = v;
  #pragma unroll
  for (int off = 1; off < 64; off <<= 1) {
    int t = __shfl_up(s, off, 64);
    if (lane >= off) s += t;
  }
  if (lane == 63) wsum[wid] = s;
  __syncthreads();
  if (wid == 0) {
    int ws = (lane < 16) ? wsum[lane] : 0;
    #pragma unroll
    for (int off = 1; off < 16; off <<= 1) {
      int t = __shfl_up(ws, off, 64);
      if (lane >= off) ws += t;
    }
    if (lane < 16) wsum[lane] = ws;
  }
  __syncthreads();
  int wexcl = (wid == 0) ? 0 : wsum[wid - 1];
  s += wexcl;
  if (i < Nn) {
    rowptr[i + 1] = s;
    dinv[i] = rsqrtf((float)v);   // v >= 1 (self loop)
  }
  if (tid == 1023) bsum[blockIdx.x] = s;
}

__global__ __launch_bounds__(64) void k_scanb(const int* __restrict__ bsum, int* __restrict__ boff,
                                              int* __restrict__ rowptr) {
  int lane = threadIdx.x;
  int v = (lane < NB) ? bsum[lane] : 0;
  int s = v;
  #pragma unroll
  for (int off = 1; off < 64; off <<= 1) {
    int u = __shfl_up(s, off, 64);
    if (lane >= off) s += u;
  }
  if (lane < NB) boff[lane] = s - v;
  if (lane == 0) rowptr[0] = 0;
}

__global__ __launch_bounds__(1024) void k_scanc(int* __restrict__ rowptr, const int* __restrict__ boff) {
  int i = blockIdx.x * 1024 + threadIdx.x;
  if (i < Nn) rowptr[i + 1] += boff[blockIdx.x];
}

// ---------------- K5: fill + inmap2 ----------------

__global__ __launch_bounds__(256) void k_build2(const int* __restrict__ ei,
    const int* __restrict__ rowptr, int* __restrict__ fill, const float* __restrict__ dinv,
    unsigned* __restrict__ cew,
    const f16* __restrict__ t, const f16* __restrict__ w2p, const float* __restrict__ b2,
    const float* __restrict__ statS, const float* __restrict__ statQ,
    const float* __restrict__ g1, const float* __restrict__ be1,
    const float* __restrict__ lw1p, const float* __restrict__ lb1p,
    const float* __restrict__ lw2p, const float* __restrict__ lb2p,
    f16* __restrict__ fused16, f16* __restrict__ h16) {
  __shared__ __attribute__((aligned(16))) f16 w2t[64 * 136];
  __shared__ __attribute__((aligned(16))) f16 dT[64 * 72];
  __shared__ __attribute__((aligned(16))) f16 wt1[16 * 72];
  __shared__ float scs[FIN], shs[FIN], sg[64];
  int tid = threadIdx.x;
  if (blockIdx.x < DEGB) {
    int e = blockIdx.x * 256 + tid;
    if (e < ETe) {
      int src, dst;
      if (e < Ee) { src = ei[e]; dst = ei[Ee + e]; }
      else { src = e - Ee; dst = src; }
      int pos = rowptr[dst] + atomicAdd(&fill[dst], 1);
      float w = dinv[src] * dinv[dst];
      f16 wh = (f16)w;
      unsigned short wb;
      __builtin_memcpy(&wb, &wh, 2);
      cew[pos] = ((unsigned)wb << 16) | (unsigned)src;
    }
    return;
  }
  // ---- inmap2 ----
  int lane = tid & 63, wid = tid >> 6;
  int row0 = (blockIdx.x - DEGB) * 64;
  for (int i = tid; i < 1088; i += 256)
    *(f16x8*)&w2t[(size_t)i * 8] = *(const f16x8*)&w2p[(size_t)i * 8];
  for (int i = tid; i < 16 * 64; i += 256) {
    int n = i & 15, k = i >> 4;
    wt1[n * 72 + k] = (n < 4) ? (f16)lw1p[k * 4 + n] : (f16)0.f;
  }
  if (tid < FIN) {
    float sv = 0.f, qv = 0.f;
    #pragma unroll
    for (int sl = 0; sl < 8; ++sl) { sv += statS[sl * 128 + tid]; qv += statQ[sl * 128 + tid]; }
    float mu = sv * (1.f / Nn);
    float var = qv * (1.f / Nn) - mu * mu;
    float rs = rsqrtf(var + 1e-5f);
    float scv = g1[tid] * rs;
    scs[tid] = scv; shs[tid] = be1[tid] - mu * scv;
  }
  __syncthreads();
  int rl = lane & 15, kb = lane >> 4;
  int arow = row0 + wid * 16 + rl;
  bool rv = arow < Nn;
  f16x8 afr[4];
  #pragma unroll
  for (int ks = 0; ks < 4; ++ks) {
    f16x8 tv;
    #pragma unroll
    for (int j = 0; j < 8; ++j) tv[j] = (f16)0.f;
    if (rv) tv = *(const f16x8*)(t + (size_t)arow * FIN + ks * 32 + kb * 8);
    f16x8 a;
    #pragma unroll
    for (int j = 0; j < 8; ++j) {
      int c = ks * 32 + kb * 8 + j;
      float v = fmaxf(fmaf((float)tv[j], scs[c], shs[c]), 0.f);
      a[j] = (f16)v;
    }
    afr[ks] = a;
  }
  f32x4 acc[4];
  #pragma unroll
  for (int i = 0; i < 4; ++i) acc[i] = (f32x4)0.f;
  #pragma unroll
  for (int ks = 0; ks < 4; ++ks) {
    #pragma unroll
    for (int ct = 0; ct < 4; ++ct) {
      f16x8 b = *(const f16x8*)&w2t[(ct * 16 + rl) * 136 + ks * 32 + kb * 8];
      acc[ct] = __builtin_amdgcn_mfma_f32_16x16x32_f16(afr[ks], b, acc[ct], 0, 0, 0);
    }
  }
  float b2v[4];
  #pragma unroll
  for (int ct = 0; ct < 4; ++ct) b2v[ct] = b2[ct * 16 + rl];
  #pragma unroll
  for (int ct = 0; ct < 4; ++ct)
    #pragma unroll
    for (int r = 0; r < 4; ++r)
      dT[(wid * 16 + kb * 4 + r) * 72 + ct * 16 + rl] = (f16)(acc[ct][r] + b2v[ct]);
  f32x4 zacc = (f32x4)0.f;
  #pragma unroll
  for (int ks = 0; ks < 2; ++ks) {
    f16x8 af = *(const f16x8*)&dT[(wid * 16 + rl) * 72 + ks * 32 + kb * 8];
    f16x8 bf = *(const f16x8*)&wt1[rl * 72 + ks * 32 + kb * 8];
    zacc = __builtin_amdgcn_mfma_f32_16x16x32_f16(af, bf, zacc, 0, 0, 0);
  }
  float lb1v = (rl < 4) ? lb1p[rl] : 0.f;
  float lw2v = (rl < 4) ? lw2p[rl] : 0.f;
  float lb2v = lb2p[0];
  #pragma unroll
  for (int r = 0; r < 4; ++r) {
    float z = zacc[r] + lb1v;
    z = (z > 0.f) ? z : 0.2f * z;
    float p = z * lw2v;
    p += __shfl_xor(p, 1, 64);
    p += __shfl_xor(p, 2, 64);
    float sgm = 1.f / (1.f + expf(-(p + lb2v)));
    if (rl == 0) sg[wid * 16 + kb * 4 + r] = sgm;
  }
  #pragma unroll
  for (int r = 0; r < 4; ++r) {
    int rw = row0 + wid * 16 + kb * 4 + r;
    if (rw < Nn) {
      float sgm = sg[wid * 16 + kb * 4 + r];
      #pragma unroll
      for (int ct = 0; ct < 4; ++ct) {
        float hn = (acc[ct][r] + b2v[ct]) * sgm;
        fused16[(size_t)rw * Dd + ct * 16 + rl] = (f16)hn;
        h16[(size_t)rw * Dd + ct * 16 + rl] = (f16)hn;
      }
    }
  }
}

// ---------------- per-layer: gather (2-stage pipelined, 32 rows/block) + MFMA + stats ----------------

__global__ __launch_bounds__(256) void k_agg(const f16* __restrict__ h16,
    const int* __restrict__ rowptr, const unsigned* __restrict__ cew,
    const float* __restrict__ bb, const f16* __restrict__ W16,
    f16* __restrict__ agg, float* __restrict__ statS, float* __restrict__ statQ) {
  __shared__ __attribute__((aligned(16))) f16 sumt[32 * 72];
  __shared__ __attribute__((aligned(16))) f16 wt[64 * 72];
  __shared__ float red[128];
  int tid = threadIdx.x, lane = tid & 63, wid = tid >> 6;
  int row0 = blockIdx.x * 32;
  for (int i = tid; i < 576; i += 256)
    *(f16x8*)&wt[(size_t)i * 8] = *(const f16x8*)&W16[(size_t)i * 8];
  if (tid < 128) red[tid] = 0.f;

  int g = lane >> 3, cl = lane & 7;
  int lrow = wid * 8 + g;
  int row = row0 + lrow;
  float acc8[8];
  #pragma unroll
  for (int c = 0; c < 8; ++c) acc8[c] = 0.f;
  if (row < Nn) {
    int s0 = rowptr[row], s1 = rowptr[row + 1];
    const unsigned* ep = cew + s0;
    int n = s1 - s0;
    // 2-stage pipeline: consume batch A while batch B's gathers are in flight
    unsigned hhA[8], ehB[8];
    #pragma unroll
    for (int k = 0; k < 8; ++k) hhA[k] = (k < n) ? ep[k] : 0u;
    #pragma unroll
    for (int k = 0; k < 8; ++k) ehB[k] = ep[8 + k];
    f16x8 vvA[8];
    #pragma unroll
    for (int k = 0; k < 8; ++k)
      vvA[k] = *(const f16x8*)(h16 + (size_t)(hhA[k] & 0xffffu) * Dd + cl * 8);
    for (int j = 0; j < n; j += 8) {
      unsigned ehC[8];
      #pragma unroll
      for (int k = 0; k < 8; ++k) ehC[k] = ep[j + 16 + k];     // headers 2 ahead (padded)
      unsigned hhB[8];
      #pragma unroll
      for (int k = 0; k < 8; ++k) hhB[k] = (j + 8 + k < n) ? ehB[k] : 0u;
      f16x8 vvB[8];
      #pragma unroll
      for (int k = 0; k < 8; ++k)
        vvB[k] = *(const f16x8*)(h16 + (size_t)(hhB[k] & 0xffffu) * Dd + cl * 8);
      #pragma unroll
      for (int k = 0; k < 8; ++k) {
        float wk = hw_to_f(hhA[k]);
        #pragma unroll
        for (int c = 0; c < 8; ++c) acc8[c] = fmaf(wk, (float)vvA[k][c], acc8[c]);
      }
      #pragma unroll
      for (int k = 0; k < 8; ++k) { hhA[k] = hhB[k]; vvA[k] = vvB[k]; ehB[k] = ehC[k]; }
    }
  }
  f16x8 hv;
  #pragma unroll
  for (int c = 0; c < 8; ++c) hv[c] = (f16)acc8[c];
  *(f16x8*)&sumt[lrow * 72 + cl * 8] = hv;
  __syncthreads();

  // MFMA: 4 waves; wave = (strip 0..1) x (ct pair 0..1)
  int rl = lane & 15, kb = lane >> 4;
  int strip = wid & 1, ch = wid >> 1;
  f32x4 acc0 = (f32x4)0.f, acc1v = (f32x4)0.f;
  #pragma unroll
  for (int ks = 0; ks < 2; ++ks) {
    f16x8 af = *(const f16x8*)&sumt[(strip * 16 + rl) * 72 + ks * 32 + kb * 8];
    f16x8 b0 = *(const f16x8*)&wt[((ch * 2) * 16 + rl) * 72 + ks * 32 + kb * 8];
    f16x8 b1 = *(const f16x8*)&wt[((ch * 2 + 1) * 16 + rl) * 72 + ks * 32 + kb * 8];
    acc0 = __builtin_amdgcn_mfma_f32_16x16x32_f16(af, b0, acc0, 0, 0, 0);
    acc1v = __builtin_amdgcn_mfma_f32_16x16x32_f16(af, b1, acc1v, 0, 0, 0);
  }
  #pragma unroll
  for (int t2 = 0; t2 < 2; ++t2) {
    f32x4 ac = t2 ? acc1v : acc0;
    int col = (ch * 2 + t2) * 16 + rl;
    float bv = bb[col];
    float s = 0.f, q = 0.f;
    #pragma unroll
    for (int r = 0; r < 4; ++r) {
      int rw = row0 + strip * 16 + kb * 4 + r;
      float o = ac[r] + bv;
      if (rw < Nn) {
        agg[(size_t)rw * Dd + col] = (f16)o;
        s += o; q += o * o;
      }
    }
    s += __shfl_xor(s, 16, 64); s += __shfl_xor(s, 32, 64);
    q += __shfl_xor(q, 16, 64); q += __shfl_xor(q, 32, 64);
    if (kb == 0) { atomicAdd(&red[col], s); atomicAdd(&red[64 + col], q); }
  }
  __syncthreads();
  if (tid < 64) {
    int slot = (blockIdx.x & 7) * 64 + tid;
    atomicAdd(&statS[slot], red[tid]);
    atomicAdd(&statQ[slot], red[64 + tid]);
  }
}

// ---------------- post: BN + MFMA learner + gate + residual (vectorized 16B I/O) ----------------

__global__ __launch_bounds__(256) void k_post(const f16* __restrict__ agg,
    const float* __restrict__ statS, const float* __restrict__ statQ,
    const float* __restrict__ gamma, const float* __restrict__ beta,
    const float* __restrict__ lw1p, const float* __restrict__ lb1p,
    const float* __restrict__ lw2p, const float* __restrict__ lb2p,
    f16* __restrict__ fused16, f16* __restrict__ h16, int mode) {
  __shared__ __attribute__((aligned(16))) f16 dT[64 * 72];
  __shared__ __attribute__((aligned(16))) f16 wt1[16 * 72];
  __shared__ float scs[Dd], shs[Dd], sg[64];
  int tid = threadIdx.x, lane = tid & 63, wid = tid >> 6;
  int row0 = blockIdx.x * 64;
  if (tid < Dd) {
    float sv = 0.f, qv = 0.f;
    #pragma unroll
    for (int sl = 0; sl < 8; ++sl) { sv += statS[sl * 64 + tid]; qv += statQ[sl * 64 + tid]; }
    float mu = sv * (1.f / Nn);
    float var = qv * (1.f / Nn) - mu * mu;
    float rs = rsqrtf(var + 1e-5f);
    float scv = gamma[tid] * rs;
    scs[tid] = scv; shs[tid] = beta[tid] - mu * scv;
  }
  for (int i = tid; i < 16 * 64; i += 256) {
    int n = i & 15, k = i >> 4;
    wt1[n * 72 + k] = (n < 4) ? (f16)lw1p[k * 4 + n] : (f16)0.f;
  }
  __syncthreads();
  int rw8 = lane >> 3, c8 = (lane & 7) * 8;
  float scv[8], shv[8];
  #pragma unroll
  for (int j = 0; j < 8; ++j) { scv[j] = scs[c8 + j]; shv[j] = shs[c8 + j]; }
  float hbv[2][8], fvv[2][8];
  #pragma unroll
  for (int p = 0; p < 2; ++p) {
    int lr = wid * 16 + p * 8 + rw8;
    int row = row0 + lr;
    f16x8 a8, f8;
    #pragma unroll
    for (int j = 0; j < 8; ++j) { a8[j] = (f16)0.f; f8[j] = (f16)0.f; }
    if (row < Nn) {
      a8 = *(const f16x8*)(agg + (size_t)row * Dd + c8);
      f8 = *(const f16x8*)(fused16 + (size_t)row * Dd + c8);
    }
    f16x8 d8;
    #pragma unroll
    for (int j = 0; j < 8; ++j) {
      float h = fmaxf(fmaf((float)a8[j], scv[j], shv[j]), 0.f);
      float f = (float)f8[j];
      hbv[p][j] = h; fvv[p][j] = f;
      d8[j] = (f16)(h - f);
    }
    *(f16x8*)&dT[lr * 72 + c8] = d8;
  }
  int rl = lane & 15, kb = lane >> 4;
  f32x4 zacc = (f32x4)0.f;
  #pragma unroll
  for (int ks = 0; ks < 2; ++ks) {
    f16x8 af = *(const f16x8*)&dT[(wid * 16 + rl) * 72 + ks * 32 + kb * 8];
    f16x8 bf = *(const f16x8*)&wt1[rl * 72 + ks * 32 + kb * 8];
    zacc = __builtin_amdgcn_mfma_f32_16x16x32_f16(af, bf, zacc, 0, 0, 0);
  }
  float lb1v = (rl < 4) ? lb1p[rl] : 0.f;
  float lw2v = (rl < 4) ? lw2p[rl] : 0.f;
  float lb2v = lb2p[0];
  #pragma unroll
  for (int r = 0; r < 4; ++r) {
    float z = zacc[r] + lb1v;
    z = (z > 0.f) ? z : 0.2f * z;
    float p = z * lw2v;
    p += __shfl_xor(p, 1, 64);
    p += __shfl_xor(p, 2, 64);
    float sgm = 1.f / (1.f + expf(-(p + lb2v)));
    if (rl == 0) sg[wid * 16 + kb * 4 + r] = sgm;
  }
  #pragma unroll
  for (int p = 0; p < 2; ++p) {
    int lr = wid * 16 + p * 8 + rw8;
    int row = row0 + lr;
    if (row < Nn) {
      float sgm = sg[lr];
      f16x8 ho, fo;
      #pragma unroll
      for (int j = 0; j < 8; ++j) {
        float hn = hbv[p][j] * sgm;
        float fn = fvv[p][j] + hn;
        ho[j] = (f16)hn; fo[j] = (f16)fn;
      }
      *(f16x8*)(fused16 + (size_t)row * Dd + c8) = fo;
      if (mode) *(f16x8*)(h16 + (size_t)row * Dd + c8) = ho;
    }
  }
}

// ---------------- output map (MFMA, both GEMMs fused, coalesced out epilogue) ----------------

__global__ __launch_bounds__(256) void k_outmap(const f16* __restrict__ fused16,
    const f16* __restrict__ ow1p, const float* __restrict__ b1,
    const f16* __restrict__ ow2p, const float* __restrict__ b2, float* __restrict__ out) {
  __shared__ __attribute__((aligned(16))) f16 fs[64 * 72];
  __shared__ __attribute__((aligned(16))) f16 w1t[128 * 72];
  __shared__ __attribute__((aligned(16))) f16 w2t[64 * 136];
  __shared__ __attribute__((aligned(16))) f16 zs[64 * 136];   // reused as float[64][68] epilogue
  int tid = threadIdx.x, lane = tid & 63, wid = tid >> 6;
  int row0 = blockIdx.x * 64;
  for (int i = tid; i < 512; i += 256) {
    int r = i >> 3, c8 = (i & 7) * 8;
    f16x8 v;
    #pragma unroll
    for (int j = 0; j < 8; ++j) v[j] = (f16)0.f;
    if (row0 + r < Nn) v = *(const f16x8*)(fused16 + (size_t)(row0 + r) * Dd + c8);
    *(f16x8*)&fs[r * 72 + c8] = v;
  }
  for (int i = tid; i < 1152; i += 256)
    *(f16x8*)&w1t[(size_t)i * 8] = *(const f16x8*)&ow1p[(size_t)i * 8];
  for (int i = tid; i < 1088; i += 256)
    *(f16x8*)&w2t[(size_t)i * 8] = *(const f16x8*)&ow2p[(size_t)i * 8];
  __syncthreads();
  int rl = lane & 15, kb = lane >> 4;
  f32x4 acc1[8];
  #pragma unroll
  for (int i = 0; i < 8; ++i) acc1[i] = (f32x4)0.f;
  #pragma unroll
  for (int ks = 0; ks < 2; ++ks) {
    f16x8 a = *(const f16x8*)&fs[(wid * 16 + rl) * 72 + ks * 32 + kb * 8];
    #pragma unroll
    for (int ct = 0; ct < 8; ++ct) {
      f16x8 b = *(const f16x8*)&w1t[(ct * 16 + rl) * 72 + ks * 32 + kb * 8];
      acc1[ct] = __builtin_amdgcn_mfma_f32_16x16x32_f16(a, b, acc1[ct], 0, 0, 0);
    }
  }
  #pragma unroll
  for (int ct = 0; ct < 8; ++ct) {
    float bv = b1[ct * 16 + rl];
    #pragma unroll
    for (int r = 0; r < 4; ++r) {
      float z = fmaxf(acc1[ct][r] + bv, 0.f);
      zs[(wid * 16 + kb * 4 + r) * 136 + ct * 16 + rl] = (f16)z;
    }
  }
  __syncthreads();
  f32x4 acc2[4];
  #pragma unroll
  for (int i = 0; i < 4; ++i) acc2[i] = (f32x4)0.f;
  #pragma unroll
  for (int ks = 0; ks < 4; ++ks) {
    f16x8 a = *(const f16x8*)&zs[(wid * 16 + rl) * 136 + ks * 32 + kb * 8];
    #pragma unroll
    for (int ct = 0; ct < 4; ++ct) {
      f16x8 b = *(const f16x8*)&w2t[(ct * 16 + rl) * 136 + ks * 32 + kb * 8];
      acc2[ct] = __builtin_amdgcn_mfma_f32_16x16x32_f16(a, b, acc2[ct], 0, 0, 0);
    }
  }
  __syncthreads();   // zs MFMA reads done -> reuse zs as float staging [64][68]
  float* fo = (float*)zs;
  #pragma unroll
  for (int ct = 0; ct < 4; ++ct) {
    float bv = b2[ct * 16 + rl];
    #pragma unroll
    for (int r = 0; r < 4; ++r)
      fo[(wid * 16 + kb * 4 + r) * 68 + ct * 16 + rl] = acc2[ct][r] + bv;
  }
  __syncthreads();
  for (int i = tid; i < 1024; i += 256) {
    int r = i >> 4, c4 = (i & 15) * 4;
    int row = row0 + r;
    if (row < Nn)
      *(float4*)(out + (size_t)row * Dd + c4) = *(const float4*)&fo[r * 68 + c4];
  }
}

// ---------------- launch ----------------

extern "C" void kernel_launch(void* const* d_in, const int* in_sizes, int n_in,
                              void* d_out, int out_size, void* d_ws, size_t ws_size,
                              hipStream_t stream) {
  const float* x      = (const float*)d_in[0];
  const int*   ei     = (const int*)d_in[1];
  const float* im_w1  = (const float*)d_in[2];
  const float* im_b1  = (const float*)d_in[3];
  const float* im_g1  = (const float*)d_in[4];
  const float* im_be1 = (const float*)d_in[5];
  const float* im_w2  = (const float*)d_in[6];
  const float* im_b2  = (const float*)d_in[7];
  const float* lw1    = (const float*)d_in[8];
  const float* lb1    = (const float*)d_in[9];
  const float* lw2    = (const float*)d_in[10];
  const float* lb2    = (const float*)d_in[11];
  const float* bw     = (const float*)d_in[12];
  const float* bb     = (const float*)d_in[13];
  const float* bg     = (const float*)d_in[14];
  const float* bbe    = (const float*)d_in[15];
  const float* om_w1  = (const float*)d_in[16];
  const float* om_b1  = (const float*)d_in[17];
  const float* om_w2  = (const float*)d_in[18];
  const float* om_b2  = (const float*)d_in[19];
  float* out = (float*)d_out;

  char* w = (char*)d_ws;
  size_t off = 0;
  auto alloc = [&](size_t bytes) -> void* {
    void* p = w + off;
    off = (off + bytes + 255) & ~(size_t)255;
    return p;
  };
  // zeroed region first
  int*   deg      = (int*)alloc((size_t)8 * Nn * 4);   // 8-way replicated
  int*   fill     = (int*)alloc((size_t)Nn * 4);
  float* statS    = (float*)alloc((size_t)(IMSTAT + LL * 512) * 4);
  float* statQ    = (float*)alloc((size_t)(IMSTAT + LL * 512) * 4);
  size_t zero_bytes = off;
  int*   rowptr   = (int*)alloc((size_t)(Nn + 1) * 4);
  int*   bsum     = (int*)alloc(64 * 4);
  int*   boff     = (int*)alloc(64 * 4);
  unsigned* cew   = (unsigned*)alloc((size_t)(ETe + 32) * 4);
  float* dinv     = (float*)alloc((size_t)Nn * 4);
  f16*   w1p      = (f16*)alloc((size_t)128 * 136 * 2);
  f16*   w2p      = (f16*)alloc((size_t)64 * 136 * 2);
  f16*   ow1p     = (f16*)alloc((size_t)128 * 72 * 2);
  f16*   ow2p     = (f16*)alloc((size_t)64 * 136 * 2);
  f16*   bwp      = (f16*)alloc((size_t)LL * 4608 * 2);
  f16*   t        = (f16*)alloc((size_t)Nn * FIN * 2);
  f16*   h16      = (f16*)alloc((size_t)Nn * Dd * 2);
  f16*   agg16    = (f16*)alloc((size_t)Nn * Dd * 2);
  f16*   fused16  = (f16*)alloc((size_t)Nn * Dd * 2);
  (void)deg; (void)fill;

  hipMemsetAsync(d_ws, 0, zero_bytes, stream);
  k_prep<<<40, 256, 0, stream>>>(im_w1, im_w2, om_w1, om_w2, bw, w1p, w2p, ow1p, ow2p, bwp);
  k_build1<<<DEGB + GEMB, 256, 0, stream>>>(ei, deg, x, w1p, im_b1, t, statS, statQ);
  k_scana<<<NB, 1024, 0, stream>>>(deg, rowptr, bsum, dinv);
  k_scanb<<<1, 64, 0, stream>>>(bsum, boff, rowptr);
  k_scanc<<<NB, 1024, 0, stream>>>(rowptr, boff);
  k_build2<<<DEGB + GEMB, 256, 0, stream>>>(ei, rowptr, fill, dinv, cew,
                                            t, w2p, im_b2, statS, statQ, im_g1, im_be1,
                                            lw1, lb1, lw2, lb2, fused16, h16);

  for (int i = 0; i < LL; ++i) {
    float* sS = statS + LSTAT(i);
    float* sQ = statQ + LSTAT(i);
    k_agg<<<AGGB, 256, 0, stream>>>(h16, rowptr, cew, bb + i * Dd,
                                    bwp + (size_t)i * 4608, agg16, sS, sQ);
    k_post<<<GEMB, 256, 0, stream>>>(agg16, sS, sQ, bg + i * Dd, bbe + i * Dd,
                                     lw1 + (size_t)(i + 1) * 256, lb1 + (size_t)(i + 1) * 4,
                                     lw2 + (size_t)(i + 1) * 4, lb2 + (i + 1),
                                     fused16, h16, (i + 1 < LL) ? 1 : 0);
  }

  k_outmap<<<GEMB, 256, 0, stream>>>(fused16, ow1p, om_b1, ow2p, om_b2, out);
}

// Round 20
// 394.245 us; speedup vs baseline: 1.0323x; 1.0323x over previous
//
#include <hip/hip_runtime.h>
#include <math.h>

#define Nn 50000
#define Ee 800000
#define ETe 850000   // E + N self loops
#define Dd 64
#define FIN 128
#define LL 8
#define NB 49        // ceil(Nn/1024)
#define DEGB 3321    // ceil(ETe/256)
#define GEMB 782     // ceil(Nn/64)

typedef _Float16 f16;
typedef f16 f16x8 __attribute__((ext_vector_type(8)));
typedef float f32x4 __attribute__((ext_vector_type(4)));

__device__ __forceinline__ float hw_to_f(unsigned h) {
  unsigned short b = (unsigned short)(h >> 16);
  f16 w;
  __builtin_memcpy(&w, &b, 2);
  return (float)w;
}

// stats layout: statS/statQ = [8][128] for input map, then per layer L: [8][64]
#define IMSTAT 1024            // 8*128
#define LSTAT(L) (IMSTAT + (L) * 512)   // 8*64 per layer

// ---------------- one-time weight prepack (f16, transposed, padded) ----------------

__global__ __launch_bounds__(256) void k_prep(const float* __restrict__ W1,
    const float* __restrict__ W2, const float* __restrict__ ow1, const float* __restrict__ ow2,
    const float* __restrict__ bwA,
    f16* __restrict__ w1p, f16* __restrict__ w2p, f16* __restrict__ ow1p,
    f16* __restrict__ ow2p, f16* __restrict__ bwp) {
  int id = blockIdx.x * 256 + threadIdx.x;
  f16x8 v;
  if (id < 2176) {
    int n = id / 17, c = id % 17;
    #pragma unroll
    for (int j = 0; j < 8; ++j) v[j] = (c == 16) ? (f16)0.f : (f16)W1[(c * 8 + j) * FIN + n];
    *(f16x8*)&w1p[n * 136 + c * 8] = v;
  } else if (id < 3264) {
    int t2 = id - 2176; int n = t2 / 17, c = t2 % 17;
    #pragma unroll
    for (int j = 0; j < 8; ++j) v[j] = (c == 16) ? (f16)0.f : (f16)W2[(c * 8 + j) * Dd + n];
    *(f16x8*)&w2p[n * 136 + c * 8] = v;
  } else if (id < 4416) {
    int t2 = id - 3264; int n = t2 / 9, c = t2 % 9;
    #pragma unroll
    for (int j = 0; j < 8; ++j) v[j] = (c == 8) ? (f16)0.f : (f16)ow1[(c * 8 + j) * FIN + n];
    *(f16x8*)&ow1p[n * 72 + c * 8] = v;
  } else if (id < 5504) {
    int t2 = id - 4416; int n = t2 / 17, c = t2 % 17;
    #pragma unroll
    for (int j = 0; j < 8; ++j) v[j] = (c == 16) ? (f16)0.f : (f16)ow2[(c * 8 + j) * Dd + n];
    *(f16x8*)&ow2p[n * 136 + c * 8] = v;
  } else if (id < 10112) {
    int t2 = id - 5504; int L = t2 / 576, r = t2 % 576, n = r / 9, c = r % 9;
    #pragma unroll
    for (int j = 0; j < 8; ++j)
      v[j] = (c == 8) ? (f16)0.f : (f16)bwA[L * 4096 + (c * 8 + j) * Dd + n];
    *(f16x8*)&bwp[(size_t)L * 4608 + n * 72 + c * 8] = v;
  }
}

// ---------------- K1: deg (8-way replicated) + ingemm ----------------

__global__ __launch_bounds__(256) void k_build1(const int* __restrict__ ei, int* __restrict__ deg,
    const float* __restrict__ x, const f16* __restrict__ w1p, const float* __restrict__ b1,
    f16* __restrict__ t, float* __restrict__ statS, float* __restrict__ statQ) {
  __shared__ __attribute__((aligned(16))) f16 wt[128 * 136];
  __shared__ float red[256];
  int tid = threadIdx.x;
  if (blockIdx.x < DEGB) {
    int e = blockIdx.x * 256 + tid;
    if (e < ETe) {
      int dst = (e < Ee) ? ei[Ee + e] : (e - Ee);
      atomicAdd(&deg[(blockIdx.x & 7) * Nn + dst], 1);
    }
    return;
  }
  int lane = tid & 63, wid = tid >> 6;
  int row0 = (blockIdx.x - DEGB) * 64;
  red[tid] = 0.f;
  for (int i = tid; i < 2176; i += 256)
    *(f16x8*)&wt[(size_t)i * 8] = *(const f16x8*)&w1p[(size_t)i * 8];
  __syncthreads();
  int rl = lane & 15, kb = lane >> 4;
  int arow = row0 + wid * 16 + rl;
  bool rv = arow < Nn;
  f16x8 afr[4];
  #pragma unroll
  for (int ks = 0; ks < 4; ++ks) {
    float4 p0 = make_float4(0.f, 0.f, 0.f, 0.f), p1 = p0;
    if (rv) {
      p0 = *(const float4*)&x[(size_t)arow * FIN + ks * 32 + kb * 8];
      p1 = *(const float4*)&x[(size_t)arow * FIN + ks * 32 + kb * 8 + 4];
    }
    f16x8 a;
    a[0] = (f16)p0.x; a[1] = (f16)p0.y; a[2] = (f16)p0.z; a[3] = (f16)p0.w;
    a[4] = (f16)p1.x; a[5] = (f16)p1.y; a[6] = (f16)p1.z; a[7] = (f16)p1.w;
    afr[ks] = a;
  }
  f32x4 acc[8];
  #pragma unroll
  for (int i = 0; i < 8; ++i) acc[i] = (f32x4)0.f;
  #pragma unroll
  for (int ks = 0; ks < 4; ++ks) {
    #pragma unroll
    for (int ct = 0; ct < 8; ++ct) {
      f16x8 b = *(const f16x8*)&wt[(ct * 16 + rl) * 136 + ks * 32 + kb * 8];
      acc[ct] = __builtin_amdgcn_mfma_f32_16x16x32_f16(afr[ks], b, acc[ct], 0, 0, 0);
    }
  }
  __syncthreads();   // reuse wt as staging tile ts[64][136]
  f16* ts = wt;
  #pragma unroll
  for (int ct = 0; ct < 8; ++ct) {
    int col = ct * 16 + rl;
    float bv = b1[col];
    float ps = 0.f, pq = 0.f;
    #pragma unroll
    for (int r = 0; r < 4; ++r) {
      int lrow = wid * 16 + kb * 4 + r;
      float v = acc[ct][r] + bv;
      ts[lrow * 136 + col] = (f16)v;
      if (row0 + lrow < Nn) { ps += v; pq += v * v; }
    }
    ps += __shfl_xor(ps, 16, 64); ps += __shfl_xor(ps, 32, 64);
    pq += __shfl_xor(pq, 16, 64); pq += __shfl_xor(pq, 32, 64);
    if (kb == 0) { atomicAdd(&red[col], ps); atomicAdd(&red[128 + col], pq); }
  }
  __syncthreads();
  for (int i = tid; i < 1024; i += 256) {
    int r = i >> 4, c8 = (i & 15) * 8;
    int row = row0 + r;
    if (row < Nn)
      *(f16x8*)(t + (size_t)row * FIN + c8) = *(const f16x8*)&ts[r * 136 + c8];
  }
  if (tid < 128) {
    int slot = (blockIdx.x & 7) * 128 + tid;
    atomicAdd(&statS[slot], red[tid]);
    atomicAdd(&statQ[slot], red[128 + tid]);
  }
}

// ---------------- scan phases ----------------

__global__ __launch_bounds__(1024) void k_scana(const int* __restrict__ deg,
    int* __restrict__ rowptr, int* __restrict__ bsum, float* __restrict__ dinv) {
  __shared__ int wsum[16];
  int tid = threadIdx.x, lane = tid & 63, wid = tid >> 6;
  int i = blockIdx.x * 1024 + tid;
  int v = 0;
  if (i < Nn) {
    #pragma unroll
    for (int sl = 0; sl < 8; ++sl) v += deg[sl * Nn + i];
  }
  int s = v;
  #pragma unroll
  for (int off = 1; off < 64; off <<= 1) {
    int t = __shfl_up(s, off, 64);
    if (lane >= off) s += t;
  }
  if (lane == 63) wsum[wid] = s;
  __syncthreads();
  if (wid == 0) {
    int ws = (lane < 16) ? wsum[lane] : 0;
    #pragma unroll
    for (int off = 1; off < 16; off <<= 1) {
      int t = __shfl_up(ws, off, 64);
      if (lane >= off) ws += t;
    }
    if (lane < 16) wsum[lane] = ws;
  }
  __syncthreads();
  int wexcl = (wid == 0) ? 0 : wsum[wid - 1];
  s += wexcl;
  if (i < Nn) {
    rowptr[i + 1] = s;
    dinv[i] = rsqrtf((float)v);   // v >= 1 (self loop)
  }
  if (tid == 1023) bsum[blockIdx.x] = s;
}

__global__ __launch_bounds__(64) void k_scanb(const int* __restrict__ bsum, int* __restrict__ boff,
                                              int* __restrict__ rowptr) {
  int lane = threadIdx.x;
  int v = (lane < NB) ? bsum[lane] : 0;
  int s = v;
  #pragma unroll
  for (int off = 1; off < 64; off <<= 1) {
    int u = __shfl_up(s, off, 64);
    if (lane >= off) s += u;
  }
  if (lane < NB) boff[lane] = s - v;
  if (lane == 0) rowptr[0] = 0;
}

__global__ __launch_bounds__(1024) void k_scanc(int* __restrict__ rowptr, const int* __restrict__ boff) {
  int i = blockIdx.x * 1024 + threadIdx.x;
  if (i < Nn) rowptr[i + 1] += boff[blockIdx.x];
}

// ---------------- K5: fill + inmap2 ----------------

__global__ __launch_bounds__(256) void k_build2(const int* __restrict__ ei,
    const int* __restrict__ rowptr, int* __restrict__ fill, const float* __restrict__ dinv,
    unsigned* __restrict__ cew,
    const f16* __restrict__ t, const f16* __restrict__ w2p, const float* __restrict__ b2,
    const float* __restrict__ statS, const float* __restrict__ statQ,
    const float* __restrict__ g1, const float* __restrict__ be1,
    const float* __restrict__ lw1p, const float* __restrict__ lb1p,
    const float* __restrict__ lw2p, const float* __restrict__ lb2p,
    f16* __restrict__ fused16, f16* __restrict__ h16) {
  __shared__ __attribute__((aligned(16))) f16 w2t[64 * 136];
  __shared__ __attribute__((aligned(16))) f16 dT[64 * 72];
  __shared__ __attribute__((aligned(16))) f16 wt1[16 * 72];
  __shared__ float scs[FIN], shs[FIN], sg[64];
  int tid = threadIdx.x;
  if (blockIdx.x < DEGB) {
    int e = blockIdx.x * 256 + tid;
    if (e < ETe) {
      int src, dst;
      if (e < Ee) { src = ei[e]; dst = ei[Ee + e]; }
      else { src = e - Ee; dst = src; }
      int pos = rowptr[dst] + atomicAdd(&fill[dst], 1);
      float w = dinv[src] * dinv[dst];
      f16 wh = (f16)w;
      unsigned short wb;
      __builtin_memcpy(&wb, &wh, 2);
      cew[pos] = ((unsigned)wb << 16) | (unsigned)src;
    }
    return;
  }
  // ---- inmap2 ----
  int lane = tid & 63, wid = tid >> 6;
  int row0 = (blockIdx.x - DEGB) * 64;
  for (int i = tid; i < 1088; i += 256)
    *(f16x8*)&w2t[(size_t)i * 8] = *(const f16x8*)&w2p[(size_t)i * 8];
  for (int i = tid; i < 16 * 64; i += 256) {
    int n = i & 15, k = i >> 4;
    wt1[n * 72 + k] = (n < 4) ? (f16)lw1p[k * 4 + n] : (f16)0.f;
  }
  if (tid < FIN) {
    float sv = 0.f, qv = 0.f;
    #pragma unroll
    for (int sl = 0; sl < 8; ++sl) { sv += statS[sl * 128 + tid]; qv += statQ[sl * 128 + tid]; }
    float mu = sv * (1.f / Nn);
    float var = qv * (1.f / Nn) - mu * mu;
    float rs = rsqrtf(var + 1e-5f);
    float scv = g1[tid] * rs;
    scs[tid] = scv; shs[tid] = be1[tid] - mu * scv;
  }
  __syncthreads();
  int rl = lane & 15, kb = lane >> 4;
  int arow = row0 + wid * 16 + rl;
  bool rv = arow < Nn;
  f16x8 afr[4];
  #pragma unroll
  for (int ks = 0; ks < 4; ++ks) {
    f16x8 tv;
    #pragma unroll
    for (int j = 0; j < 8; ++j) tv[j] = (f16)0.f;
    if (rv) tv = *(const f16x8*)(t + (size_t)arow * FIN + ks * 32 + kb * 8);
    f16x8 a;
    #pragma unroll
    for (int j = 0; j < 8; ++j) {
      int c = ks * 32 + kb * 8 + j;
      float v = fmaxf(fmaf((float)tv[j], scs[c], shs[c]), 0.f);
      a[j] = (f16)v;
    }
    afr[ks] = a;
  }
  f32x4 acc[4];
  #pragma unroll
  for (int i = 0; i < 4; ++i) acc[i] = (f32x4)0.f;
  #pragma unroll
  for (int ks = 0; ks < 4; ++ks) {
    #pragma unroll
    for (int ct = 0; ct < 4; ++ct) {
      f16x8 b = *(const f16x8*)&w2t[(ct * 16 + rl) * 136 + ks * 32 + kb * 8];
      acc[ct] = __builtin_amdgcn_mfma_f32_16x16x32_f16(afr[ks], b, acc[ct], 0, 0, 0);
    }
  }
  float b2v[4];
  #pragma unroll
  for (int ct = 0; ct < 4; ++ct) b2v[ct] = b2[ct * 16 + rl];
  #pragma unroll
  for (int ct = 0; ct < 4; ++ct)
    #pragma unroll
    for (int r = 0; r < 4; ++r)
      dT[(wid * 16 + kb * 4 + r) * 72 + ct * 16 + rl] = (f16)(acc[ct][r] + b2v[ct]);
  f32x4 zacc = (f32x4)0.f;
  #pragma unroll
  for (int ks = 0; ks < 2; ++ks) {
    f16x8 af = *(const f16x8*)&dT[(wid * 16 + rl) * 72 + ks * 32 + kb * 8];
    f16x8 bf = *(const f16x8*)&wt1[rl * 72 + ks * 32 + kb * 8];
    zacc = __builtin_amdgcn_mfma_f32_16x16x32_f16(af, bf, zacc, 0, 0, 0);
  }
  float lb1v = (rl < 4) ? lb1p[rl] : 0.f;
  float lw2v = (rl < 4) ? lw2p[rl] : 0.f;
  float lb2v = lb2p[0];
  #pragma unroll
  for (int r = 0; r < 4; ++r) {
    float z = zacc[r] + lb1v;
    z = (z > 0.f) ? z : 0.2f * z;
    float p = z * lw2v;
    p += __shfl_xor(p, 1, 64);
    p += __shfl_xor(p, 2, 64);
    float sgm = 1.f / (1.f + expf(-(p + lb2v)));
    if (rl == 0) sg[wid * 16 + kb * 4 + r] = sgm;
  }
  #pragma unroll
  for (int r = 0; r < 4; ++r) {
    int rw = row0 + wid * 16 + kb * 4 + r;
    if (rw < Nn) {
      float sgm = sg[wid * 16 + kb * 4 + r];
      #pragma unroll
      for (int ct = 0; ct < 4; ++ct) {
        float hn = (acc[ct][r] + b2v[ct]) * sgm;
        fused16[(size_t)rw * Dd + ct * 16 + rl] = (f16)hn;
        h16[(size_t)rw * Dd + ct * 16 + rl] = (f16)hn;
      }
    }
  }
}

// ---------------- per-layer: gather (2-stage pipelined, 64 rows, 512 thr) + MFMA + stats ----------------

__global__ __launch_bounds__(512) void k_agg(const f16* __restrict__ h16,
    const int* __restrict__ rowptr, const unsigned* __restrict__ cew,
    const float* __restrict__ bb, const f16* __restrict__ W16,
    f16* __restrict__ agg, float* __restrict__ statS, float* __restrict__ statQ) {
  __shared__ __attribute__((aligned(16))) f16 sumt[64 * 72];
  __shared__ __attribute__((aligned(16))) f16 wt[64 * 72];
  __shared__ float red[128];
  int tid = threadIdx.x, lane = tid & 63, wid = tid >> 6;
  int row0 = blockIdx.x * 64;
  {
    int n = tid & 63, kb8 = tid >> 6;
    *(f16x8*)&wt[n * 72 + kb8 * 8] = *(const f16x8*)&W16[n * 72 + kb8 * 8];
  }
  if (tid < 128) red[tid] = 0.f;

  int g = lane >> 3, cl = lane & 7;
  int lrow = wid * 8 + g;
  int row = row0 + lrow;
  float acc8[8];
  #pragma unroll
  for (int c = 0; c < 8; ++c) acc8[c] = 0.f;
  if (row < Nn) {
    int s0 = rowptr[row], s1 = rowptr[row + 1];
    const unsigned* ep = cew + s0;
    int n = s1 - s0;
    // 2-stage pipeline: consume batch A while batch B's gathers are in flight
    unsigned hhA[8], ehB[8];
    #pragma unroll
    for (int k = 0; k < 8; ++k) hhA[k] = (k < n) ? ep[k] : 0u;
    #pragma unroll
    for (int k = 0; k < 8; ++k) ehB[k] = ep[8 + k];
    f16x8 vvA[8];
    #pragma unroll
    for (int k = 0; k < 8; ++k)
      vvA[k] = *(const f16x8*)(h16 + (size_t)(hhA[k] & 0xffffu) * Dd + cl * 8);
    for (int j = 0; j < n; j += 8) {
      unsigned ehC[8];
      #pragma unroll
      for (int k = 0; k < 8; ++k) ehC[k] = ep[j + 16 + k];     // headers 2 ahead (padded)
      unsigned hhB[8];
      #pragma unroll
      for (int k = 0; k < 8; ++k) hhB[k] = (j + 8 + k < n) ? ehB[k] : 0u;
      f16x8 vvB[8];
      #pragma unroll
      for (int k = 0; k < 8; ++k)
        vvB[k] = *(const f16x8*)(h16 + (size_t)(hhB[k] & 0xffffu) * Dd + cl * 8);
      #pragma unroll
      for (int k = 0; k < 8; ++k) {
        float wk = hw_to_f(hhA[k]);
        #pragma unroll
        for (int c = 0; c < 8; ++c) acc8[c] = fmaf(wk, (float)vvA[k][c], acc8[c]);
      }
      #pragma unroll
      for (int k = 0; k < 8; ++k) { hhA[k] = hhB[k]; vvA[k] = vvB[k]; ehB[k] = ehC[k]; }
    }
  }
  f16x8 hv;
  #pragma unroll
  for (int c = 0; c < 8; ++c) hv[c] = (f16)acc8[c];
  *(f16x8*)&sumt[lrow * 72 + cl * 8] = hv;
  __syncthreads();

  // MFMA: 8 waves; wave = (strip 0..3) x (ct half 0..1)
  int rl = lane & 15, kb = lane >> 4;
  int strip = wid & 3, ch = wid >> 2;
  f32x4 acc0 = (f32x4)0.f, acc1v = (f32x4)0.f;
  #pragma unroll
  for (int ks = 0; ks < 2; ++ks) {
    f16x8 af = *(const f16x8*)&sumt[(strip * 16 + rl) * 72 + ks * 32 + kb * 8];
    f16x8 b0 = *(const f16x8*)&wt[((ch * 2) * 16 + rl) * 72 + ks * 32 + kb * 8];
    f16x8 b1 = *(const f16x8*)&wt[((ch * 2 + 1) * 16 + rl) * 72 + ks * 32 + kb * 8];
    acc0 = __builtin_amdgcn_mfma_f32_16x16x32_f16(af, b0, acc0, 0, 0, 0);
    acc1v = __builtin_amdgcn_mfma_f32_16x16x32_f16(af, b1, acc1v, 0, 0, 0);
  }
  #pragma unroll
  for (int t2 = 0; t2 < 2; ++t2) {
    f32x4 ac = t2 ? acc1v : acc0;
    int col = (ch * 2 + t2) * 16 + rl;
    float bv = bb[col];
    float s = 0.f, q = 0.f;
    #pragma unroll
    for (int r = 0; r < 4; ++r) {
      int rw = row0 + strip * 16 + kb * 4 + r;
      float o = ac[r] + bv;
      if (rw < Nn) {
        agg[(size_t)rw * Dd + col] = (f16)o;
        s += o; q += o * o;
      }
    }
    s += __shfl_xor(s, 16, 64); s += __shfl_xor(s, 32, 64);
    q += __shfl_xor(q, 16, 64); q += __shfl_xor(q, 32, 64);
    if (kb == 0) { atomicAdd(&red[col], s); atomicAdd(&red[64 + col], q); }
  }
  __syncthreads();
  if (tid < 64) {
    int slot = (blockIdx.x & 7) * 64 + tid;
    atomicAdd(&statS[slot], red[tid]);
    atomicAdd(&statQ[slot], red[64 + tid]);
  }
}

// ---------------- post: BN + MFMA learner + gate + residual (vectorized 16B I/O) ----------------

__global__ __launch_bounds__(256) void k_post(const f16* __restrict__ agg,
    const float* __restrict__ statS, const float* __restrict__ statQ,
    const float* __restrict__ gamma, const float* __restrict__ beta,
    const float* __restrict__ lw1p, const float* __restrict__ lb1p,
    const float* __restrict__ lw2p, const float* __restrict__ lb2p,
    f16* __restrict__ fused16, f16* __restrict__ h16, int mode) {
  __shared__ __attribute__((aligned(16))) f16 dT[64 * 72];
  __shared__ __attribute__((aligned(16))) f16 wt1[16 * 72];
  __shared__ float scs[Dd], shs[Dd], sg[64];
  int tid = threadIdx.x, lane = tid & 63, wid = tid >> 6;
  int row0 = blockIdx.x * 64;
  if (tid < Dd) {
    float sv = 0.f, qv = 0.f;
    #pragma unroll
    for (int sl = 0; sl < 8; ++sl) { sv += statS[sl * 64 + tid]; qv += statQ[sl * 64 + tid]; }
    float mu = sv * (1.f / Nn);
    float var = qv * (1.f / Nn) - mu * mu;
    float rs = rsqrtf(var + 1e-5f);
    float scv = gamma[tid] * rs;
    scs[tid] = scv; shs[tid] = beta[tid] - mu * scv;
  }
  for (int i = tid; i < 16 * 64; i += 256) {
    int n = i & 15, k = i >> 4;
    wt1[n * 72 + k] = (n < 4) ? (f16)lw1p[k * 4 + n] : (f16)0.f;
  }
  __syncthreads();
  int rw8 = lane >> 3, c8 = (lane & 7) * 8;
  float scv[8], shv[8];
  #pragma unroll
  for (int j = 0; j < 8; ++j) { scv[j] = scs[c8 + j]; shv[j] = shs[c8 + j]; }
  float hbv[2][8], fvv[2][8];
  #pragma unroll
  for (int p = 0; p < 2; ++p) {
    int lr = wid * 16 + p * 8 + rw8;
    int row = row0 + lr;
    f16x8 a8, f8;
    #pragma unroll
    for (int j = 0; j < 8; ++j) { a8[j] = (f16)0.f; f8[j] = (f16)0.f; }
    if (row < Nn) {
      a8 = *(const f16x8*)(agg + (size_t)row * Dd + c8);
      f8 = *(const f16x8*)(fused16 + (size_t)row * Dd + c8);
    }
    f16x8 d8;
    #pragma unroll
    for (int j = 0; j < 8; ++j) {
      float h = fmaxf(fmaf((float)a8[j], scv[j], shv[j]), 0.f);
      float f = (float)f8[j];
      hbv[p][j] = h; fvv[p][j] = f;
      d8[j] = (f16)(h - f);
    }
    *(f16x8*)&dT[lr * 72 + c8] = d8;
  }
  int rl = lane & 15, kb = lane >> 4;
  f32x4 zacc = (f32x4)0.f;
  #pragma unroll
  for (int ks = 0; ks < 2; ++ks) {
    f16x8 af = *(const f16x8*)&dT[(wid * 16 + rl) * 72 + ks * 32 + kb * 8];
    f16x8 bf = *(const f16x8*)&wt1[rl * 72 + ks * 32 + kb * 8];
    zacc = __builtin_amdgcn_mfma_f32_16x16x32_f16(af, bf, zacc, 0, 0, 0);
  }
  float lb1v = (rl < 4) ? lb1p[rl] : 0.f;
  float lw2v = (rl < 4) ? lw2p[rl] : 0.f;
  float lb2v = lb2p[0];
  #pragma unroll
  for (int r = 0; r < 4; ++r) {
    float z = zacc[r] + lb1v;
    z = (z > 0.f) ? z : 0.2f * z;
    float p = z * lw2v;
    p += __shfl_xor(p, 1, 64);
    p += __shfl_xor(p, 2, 64);
    float sgm = 1.f / (1.f + expf(-(p + lb2v)));
    if (rl == 0) sg[wid * 16 + kb * 4 + r] = sgm;
  }
  #pragma unroll
  for (int p = 0; p < 2; ++p) {
    int lr = wid * 16 + p * 8 + rw8;
    int row = row0 + lr;
    if (row < Nn) {
      float sgm = sg[lr];
      f16x8 ho, fo;
      #pragma unroll
      for (int j = 0; j < 8; ++j) {
        float hn = hbv[p][j] * sgm;
        float fn = fvv[p][j] + hn;
        ho[j] = (f16)hn; fo[j] = (f16)fn;
      }
      *(f16x8*)(fused16 + (size_t)row * Dd + c8) = fo;
      if (mode) *(f16x8*)(h16 + (size_t)row * Dd + c8) = ho;
    }
  }
}

// ---------------- output map (MFMA, both GEMMs fused, coalesced out epilogue) ----------------

__global__ __launch_bounds__(256) void k_outmap(const f16* __restrict__ fused16,
    const f16* __restrict__ ow1p, const float* __restrict__ b1,
    const f16* __restrict__ ow2p, const float* __restrict__ b2, float* __restrict__ out) {
  __shared__ __attribute__((aligned(16))) f16 fs[64 * 72];
  __shared__ __attribute__((aligned(16))) f16 w1t[128 * 72];
  __shared__ __attribute__((aligned(16))) f16 w2t[64 * 136];
  __shared__ __attribute__((aligned(16))) f16 zs[64 * 136];   // reused as float[64][68] epilogue
  int tid = threadIdx.x, lane = tid & 63, wid = tid >> 6;
  int row0 = blockIdx.x * 64;
  for (int i = tid; i < 512; i += 256) {
    int r = i >> 3, c8 = (i & 7) * 8;
    f16x8 v;
    #pragma unroll
    for (int j = 0; j < 8; ++j) v[j] = (f16)0.f;
    if (row0 + r < Nn) v = *(const f16x8*)(fused16 + (size_t)(row0 + r) * Dd + c8);
    *(f16x8*)&fs[r * 72 + c8] = v;
  }
  for (int i = tid; i < 1152; i += 256)
    *(f16x8*)&w1t[(size_t)i * 8] = *(const f16x8*)&ow1p[(size_t)i * 8];
  for (int i = tid; i < 1088; i += 256)
    *(f16x8*)&w2t[(size_t)i * 8] = *(const f16x8*)&ow2p[(size_t)i * 8];
  __syncthreads();
  int rl = lane & 15, kb = lane >> 4;
  f32x4 acc1[8];
  #pragma unroll
  for (int i = 0; i < 8; ++i) acc1[i] = (f32x4)0.f;
  #pragma unroll
  for (int ks = 0; ks < 2; ++ks) {
    f16x8 a = *(const f16x8*)&fs[(wid * 16 + rl) * 72 + ks * 32 + kb * 8];
    #pragma unroll
    for (int ct = 0; ct < 8; ++ct) {
      f16x8 b = *(const f16x8*)&w1t[(ct * 16 + rl) * 72 + ks * 32 + kb * 8];
      acc1[ct] = __builtin_amdgcn_mfma_f32_16x16x32_f16(a, b, acc1[ct], 0, 0, 0);
    }
  }
  #pragma unroll
  for (int ct = 0; ct < 8; ++ct) {
    float bv = b1[ct * 16 + rl];
    #pragma unroll
    for (int r = 0; r < 4; ++r) {
      float z = fmaxf(acc1[ct][r] + bv, 0.f);
      zs[(wid * 16 + kb * 4 + r) * 136 + ct * 16 + rl] = (f16)z;
    }
  }
  __syncthreads();
  f32x4 acc2[4];
  #pragma unroll
  for (int i = 0; i < 4; ++i) acc2[i] = (f32x4)0.f;
  #pragma unroll
  for (int ks = 0; ks < 4; ++ks) {
    f16x8 a = *(const f16x8*)&zs[(wid * 16 + rl) * 136 + ks * 32 + kb * 8];
    #pragma unroll
    for (int ct = 0; ct < 4; ++ct) {
      f16x8 b = *(const f16x8*)&w2t[(ct * 16 + rl) * 136 + ks * 32 + kb * 8];
      acc2[ct] = __builtin_amdgcn_mfma_f32_16x16x32_f16(a, b, acc2[ct], 0, 0, 0);
    }
  }
  __syncthreads();   // zs MFMA reads done -> reuse zs as float staging [64][68]
  float* fo = (float*)zs;
  #pragma unroll
  for (int ct = 0; ct < 4; ++ct) {
    float bv = b2[ct * 16 + rl];
    #pragma unroll
    for (int r = 0; r < 4; ++r)
      fo[(wid * 16 + kb * 4 + r) * 68 + ct * 16 + rl] = acc2[ct][r] + bv;
  }
  __syncthreads();
  for (int i = tid; i < 1024; i += 256) {
    int r = i >> 4, c4 = (i & 15) * 4;
    int row = row0 + r;
    if (row < Nn)
      *(float4*)(out + (size_t)row * Dd + c4) = *(const float4*)&fo[r * 68 + c4];
  }
}

// ---------------- launch ----------------

extern "C" void kernel_launch(void* const* d_in, const int* in_sizes, int n_in,
                              void* d_out, int out_size, void* d_ws, size_t ws_size,
                              hipStream_t stream) {
  const float* x      = (const float*)d_in[0];
  const int*   ei     = (const int*)d_in[1];
  const float* im_w1  = (const float*)d_in[2];
  const float* im_b1  = (const float*)d_in[3];
  const float* im_g1  = (const float*)d_in[4];
  const float* im_be1 = (const float*)d_in[5];
  const float* im_w2  = (const float*)d_in[6];
  const float* im_b2  = (const float*)d_in[7];
  const float* lw1    = (const float*)d_in[8];
  const float* lb1    = (const float*)d_in[9];
  const float* lw2    = (const float*)d_in[10];
  const float* lb2    = (const float*)d_in[11];
  const float* bw     = (const float*)d_in[12];
  const float* bb     = (const float*)d_in[13];
  const float* bg     = (const float*)d_in[14];
  const float* bbe    = (const float*)d_in[15];
  const float* om_w1  = (const float*)d_in[16];
  const float* om_b1  = (const float*)d_in[17];
  const float* om_w2  = (const float*)d_in[18];
  const float* om_b2  = (const float*)d_in[19];
  float* out = (float*)d_out;

  char* w = (char*)d_ws;
  size_t off = 0;
  auto alloc = [&](size_t bytes) -> void* {
    void* p = w + off;
    off = (off + bytes + 255) & ~(size_t)255;
    return p;
  };
  // zeroed region first
  int*   deg      = (int*)alloc((size_t)8 * Nn * 4);   // 8-way replicated
  int*   fill     = (int*)alloc((size_t)Nn * 4);
  float* statS    = (float*)alloc((size_t)(IMSTAT + LL * 512) * 4);
  float* statQ    = (float*)alloc((size_t)(IMSTAT + LL * 512) * 4);
  size_t zero_bytes = off;
  int*   rowptr   = (int*)alloc((size_t)(Nn + 1) * 4);
  int*   bsum     = (int*)alloc(64 * 4);
  int*   boff     = (int*)alloc(64 * 4);
  unsigned* cew   = (unsigned*)alloc((size_t)(ETe + 32) * 4);
  float* dinv     = (float*)alloc((size_t)Nn * 4);
  f16*   w1p      = (f16*)alloc((size_t)128 * 136 * 2);
  f16*   w2p      = (f16*)alloc((size_t)64 * 136 * 2);
  f16*   ow1p     = (f16*)alloc((size_t)128 * 72 * 2);
  f16*   ow2p     = (f16*)alloc((size_t)64 * 136 * 2);
  f16*   bwp      = (f16*)alloc((size_t)LL * 4608 * 2);
  f16*   t        = (f16*)alloc((size_t)Nn * FIN * 2);
  f16*   h16      = (f16*)alloc((size_t)Nn * Dd * 2);
  f16*   agg16    = (f16*)alloc((size_t)Nn * Dd * 2);
  f16*   fused16  = (f16*)alloc((size_t)Nn * Dd * 2);
  (void)deg; (void)fill;

  hipMemsetAsync(d_ws, 0, zero_bytes, stream);
  k_prep<<<40, 256, 0, stream>>>(im_w1, im_w2, om_w1, om_w2, bw, w1p, w2p, ow1p, ow2p, bwp);
  k_build1<<<DEGB + GEMB, 256, 0, stream>>>(ei, deg, x, w1p, im_b1, t, statS, statQ);
  k_scana<<<NB, 1024, 0, stream>>>(deg, rowptr, bsum, dinv);
  k_scanb<<<1, 64, 0, stream>>>(bsum, boff, rowptr);
  k_scanc<<<NB, 1024, 0, stream>>>(rowptr, boff);
  k_build2<<<DEGB + GEMB, 256, 0, stream>>>(ei, rowptr, fill, dinv, cew,
                                            t, w2p, im_b2, statS, statQ, im_g1, im_be1,
                                            lw1, lb1, lw2, lb2, fused16, h16);

  for (int i = 0; i < LL; ++i) {
    float* sS = statS + LSTAT(i);
    float* sQ = statQ + LSTAT(i);
    k_agg<<<GEMB, 512, 0, stream>>>(h16, rowptr, cew, bb + i * Dd,
                                    bwp + (size_t)i * 4608, agg16, sS, sQ);
    k_post<<<GEMB, 256, 0, stream>>>(agg16, sS, sQ, bg + i * Dd, bbe + i * Dd,
                                     lw1 + (size_t)(i + 1) * 256, lb1 + (size_t)(i + 1) * 4,
                                     lw2 + (size_t)(i + 1) * 4, lb2 + (i + 1),
                                     fused16, h16, (i + 1 < LL) ? 1 : 0);
  }

  k_outmap<<<GEMB, 256, 0, stream>>>(fused16, ow1p, om_b1, ow2p, om_b2, out);
}